// Round 1
// baseline (290.564 us; speedup 1.0000x reference)
//
#include <hip/hip_runtime.h>
#include <hip/hip_bf16.h>
#include <math.h>

#define BB 4
#define PP 4096
#define HH 256
#define RTILE 16
#define INV_T (1.0f/0.07f)
#define NEGINF (-1e30f)

__device__ __forceinline__ float blockReduceSum(float v, float* lds){
  #pragma unroll
  for (int off = 32; off; off >>= 1) v += __shfl_xor(v, off);
  int wave = threadIdx.x >> 6;
  if ((threadIdx.x & 63) == 0) lds[wave] = v;
  __syncthreads();
  float r = lds[0] + lds[1] + lds[2] + lds[3];
  __syncthreads();
  return r;
}

// ---------------- K1: deterministic compaction ----------------
__global__ void k_compact(const int* __restrict__ labels, int* __restrict__ meta,
                          int* __restrict__ posIdx, int* __restrict__ negIdx){
  int b = blockIdx.x;
  const int* lab = labels + b * PP;
  __shared__ int wP[4], wN[4], wV[4];
  __shared__ int basePos, baseNeg, baseVal;
  int tid = threadIdx.x, wave = tid >> 6, lane = tid & 63;
  if (tid == 0){ basePos = 0; baseNeg = 0; baseVal = 0; }
  __syncthreads();
  for (int c = 0; c < PP; c += 256){
    int p = c + tid;
    int l = lab[p];
    bool isP = (l == 1), isN = (l == 0), isV = (l != -100);
    unsigned long long bP = __ballot(isP), bN = __ballot(isN), bV = __ballot(isV);
    unsigned long long lt = (1ull << lane) - 1ull;
    if (lane == 0){ wP[wave] = __popcll(bP); wN[wave] = __popcll(bN); wV[wave] = __popcll(bV); }
    __syncthreads();
    int offP = 0, offN = 0;
    for (int w = 0; w < wave; w++){ offP += wP[w]; offN += wN[w]; }
    if (isP) posIdx[b*PP + basePos + offP + __popcll(bP & lt)] = p;
    if (isN) negIdx[b*PP + baseNeg + offN + __popcll(bN & lt)] = p;
    __syncthreads();
    if (tid == 0){
      basePos += wP[0] + wP[1] + wP[2] + wP[3];
      baseNeg += wN[0] + wN[1] + wN[2] + wN[3];
      baseVal += wV[0] + wV[1] + wV[2] + wV[3];
    }
    __syncthreads();
  }
  if (tid == 0){
    int Np = basePos, Nn = baseNeg, nv = baseVal;
    meta[b*4+0] = Np;
    meta[b*4+1] = Nn;
    meta[b*4+2] = (nv >= 2 && Np > 0 && Nn > 0) ? 1 : 0;
    meta[b*4+3] = nv;
  }
}

// ---------------- K2: normalize scales, diag, transposed neg matrix ----------------
// blocks [0, B*P)        -> positive rows: gscale + diag
// blocks [B*P, 2*B*P)    -> negative cols: normalized english written transposed
__global__ void k_gather(const float* __restrict__ greek, const float* __restrict__ english,
                         const int* __restrict__ meta, const int* __restrict__ posIdx,
                         const int* __restrict__ negIdx,
                         float* __restrict__ gscale, float* __restrict__ EnegT,
                         float* __restrict__ diag){
  __shared__ float lds[4];
  int tid = threadIdx.x;
  int gb = blockIdx.x;
  int idxInHalf = gb % (BB * PP);
  bool isPosHalf = gb < (BB * PP);
  int b = idxInHalf / PP;
  int i = idxInHalf % PP;
  int Np = meta[b*4+0], Nn = meta[b*4+1];
  if (isPosHalf){
    if (i >= Np) return;
    int p = posIdx[b*PP + i];
    size_t base = ((size_t)b * PP + p) * HH;
    float gv = greek[base + tid];
    float ssg = blockReduceSum(gv * gv, lds);
    float gs = 1.0f / fmaxf(sqrtf(ssg), 1e-12f);
    float gn = gv * gs;
    if (tid == 0) gscale[b*PP + i] = gs;
    float ev = english[base + tid];
    float sse = blockReduceSum(ev * ev, lds);
    float es = 1.0f / fmaxf(sqrtf(sse), 1e-12f);
    float en = ev * es;
    float d = blockReduceSum(gn * en, lds);
    if (tid == 0) diag[b*PP + i] = d;
  } else {
    if (i >= Nn) return;
    int q = negIdx[b*PP + i];
    size_t base = ((size_t)b * PP + q) * HH;
    float ev = english[base + tid];
    float sse = blockReduceSum(ev * ev, lds);
    float es = 1.0f / fmaxf(sqrtf(sse), 1e-12f);
    EnegT[((size_t)b * HH + tid) * PP + i] = ev * es;
  }
}

// ---------------- K3: LSE over negatives (register-tiled GEMV batch) ----------------
__global__ void k_loss(const float* __restrict__ greek, const float* __restrict__ gscale,
                       const int* __restrict__ posIdx,
                       const float* __restrict__ EnegT,
                       const float* __restrict__ diag, const int* __restrict__ meta,
                       float* __restrict__ loss){
  int b = blockIdx.y;
  int i0 = blockIdx.x * RTILE;
  int tid = threadIdx.x;
  int Np = meta[b*4+0], Nn = meta[b*4+1], ok = meta[b*4+2];
  if (!ok || i0 >= Np){
    if (tid < RTILE) loss[b*PP + i0 + tid] = 0.0f;
    return;
  }
  __shared__ float gLT[HH][20];   // [h][row], padded to 20 -> 16B-aligned float4 rows
  __shared__ float wm[4][RTILE], wsum[4][RTILE];

  for (int idx = tid; idx < RTILE * HH; idx += 256){
    int r = idx >> 8, h = idx & 255;
    float v = 0.0f;
    int i = i0 + r;
    if (i < Np){
      int p = posIdx[b*PP + i];
      v = greek[((size_t)b * PP + p) * HH + h] * gscale[b*PP + i];
    }
    gLT[h][r] = v;
  }
  __syncthreads();

  float m[RTILE], s[RTILE];
  #pragma unroll
  for (int r = 0; r < RTILE; r++){ m[r] = NEGINF; s[r] = 0.0f; }

  const float* ET = EnegT + (size_t)b * HH * PP;
  int passes = (Nn + 1023) >> 10;
  for (int c = 0; c < passes; c++){
    int j0 = (c << 10) + (tid << 2);
    if (j0 < Nn){
      float acc[RTILE][4];
      #pragma unroll
      for (int r = 0; r < RTILE; r++){ acc[r][0]=0.f; acc[r][1]=0.f; acc[r][2]=0.f; acc[r][3]=0.f; }
      for (int h = 0; h < HH; h++){
        float4 ev = *reinterpret_cast<const float4*>(ET + (size_t)h * PP + j0);
        #pragma unroll
        for (int rq = 0; rq < RTILE/4; rq++){
          float4 g4 = *reinterpret_cast<const float4*>(&gLT[h][rq*4]);
          acc[rq*4+0][0] += g4.x*ev.x; acc[rq*4+0][1] += g4.x*ev.y; acc[rq*4+0][2] += g4.x*ev.z; acc[rq*4+0][3] += g4.x*ev.w;
          acc[rq*4+1][0] += g4.y*ev.x; acc[rq*4+1][1] += g4.y*ev.y; acc[rq*4+1][2] += g4.y*ev.z; acc[rq*4+1][3] += g4.y*ev.w;
          acc[rq*4+2][0] += g4.z*ev.x; acc[rq*4+2][1] += g4.z*ev.y; acc[rq*4+2][2] += g4.z*ev.z; acc[rq*4+2][3] += g4.z*ev.w;
          acc[rq*4+3][0] += g4.w*ev.x; acc[rq*4+3][1] += g4.w*ev.y; acc[rq*4+3][2] += g4.w*ev.z; acc[rq*4+3][3] += g4.w*ev.w;
        }
      }
      #pragma unroll
      for (int r = 0; r < RTILE; r++){
        float l0 = (j0+0 < Nn) ? acc[r][0]*INV_T : NEGINF;
        float l1 = (j0+1 < Nn) ? acc[r][1]*INV_T : NEGINF;
        float l2 = (j0+2 < Nn) ? acc[r][2]*INV_T : NEGINF;
        float l3 = (j0+3 < Nn) ? acc[r][3]*INV_T : NEGINF;
        float mx = fmaxf(fmaxf(l0,l1), fmaxf(l2,l3));
        float mn = fmaxf(m[r], mx);   // >= l0 > NEGINF, safe
        s[r] = s[r]*expf(m[r]-mn) + expf(l0-mn) + expf(l1-mn) + expf(l2-mn) + expf(l3-mn);
        m[r] = mn;
      }
    }
  }

  // wave butterfly combine of (m,s)
  #pragma unroll
  for (int off = 32; off; off >>= 1){
    #pragma unroll
    for (int r = 0; r < RTILE; r++){
      float m2 = __shfl_xor(m[r], off);
      float s2 = __shfl_xor(s[r], off);
      float mn = fmaxf(m[r], m2);    // NEGINF-NEGINF = 0 -> exp(0)=1, s stays 0: safe
      s[r] = s[r]*expf(m[r]-mn) + s2*expf(m2-mn);
      m[r] = mn;
    }
  }
  int wave = tid >> 6, lane = tid & 63;
  if (lane == 0){
    #pragma unroll
    for (int r = 0; r < RTILE; r++){ wm[wave][r] = m[r]; wsum[wave][r] = s[r]; }
  }
  __syncthreads();
  if (tid < RTILE){
    int r = tid;
    float M = NEGINF, S = 0.0f;
    #pragma unroll
    for (int w = 0; w < 4; w++){
      float m2 = wm[w][r], s2 = wsum[w][r];
      float mn = fmaxf(M, m2);
      S = S*expf(M-mn) + s2*expf(m2-mn);
      M = mn;
    }
    float out = 0.0f;
    int i = i0 + r;
    if (i < Np){
      float dl = diag[b*PP + i] * INV_T;
      float mn = fmaxf(M, dl);
      float lse = mn + logf(S*expf(M-mn) + expf(dl-mn));
      out = lse - dl;
    }
    loss[b*PP + i0 + r] = out;
  }
}

// ---------------- K4: deterministic final reduce ----------------
__global__ void k_final(const float* __restrict__ loss, const int* __restrict__ meta,
                        float* __restrict__ out){
  __shared__ float lds[4];
  int tid = threadIdx.x;
  float v = 0.0f;
  for (int idx = tid; idx < BB*PP; idx += 256) v += loss[idx];
  float total = blockReduceSum(v, lds);
  if (tid == 0){
    int count = 0;
    for (int b = 0; b < BB; b++) if (meta[b*4+2]) count += meta[b*4+0];
    out[0] = (count == 0) ? 0.0f : total / (float)count;
  }
}

extern "C" void kernel_launch(void* const* d_in, const int* in_sizes, int n_in,
                              void* d_out, int out_size, void* d_ws, size_t ws_size,
                              hipStream_t stream){
  const float* greek   = (const float*)d_in[0];
  const float* english = (const float*)d_in[1];
  const int*   labels  = (const int*)d_in[2];
  float* out = (float*)d_out;

  char* ws = (char*)d_ws;
  size_t off = 0;
  float* EnegT  = (float*)(ws + off); off += (size_t)BB*HH*PP*sizeof(float);   // 16 MB
  float* diag   = (float*)(ws + off); off += (size_t)BB*PP*sizeof(float);
  float* loss   = (float*)(ws + off); off += (size_t)BB*PP*sizeof(float);
  float* gscale = (float*)(ws + off); off += (size_t)BB*PP*sizeof(float);
  int*   posIdx = (int*)(ws + off);   off += (size_t)BB*PP*sizeof(int);
  int*   negIdx = (int*)(ws + off);   off += (size_t)BB*PP*sizeof(int);
  int*   meta   = (int*)(ws + off);   off += 64;

  k_compact<<<BB, 256, 0, stream>>>(labels, meta, posIdx, negIdx);
  k_gather<<<2*BB*PP, 256, 0, stream>>>(greek, english, meta, posIdx, negIdx,
                                        gscale, EnegT, diag);
  dim3 g3(PP/RTILE, BB);
  k_loss<<<g3, 256, 0, stream>>>(greek, gscale, posIdx, EnegT, diag, meta, loss);
  k_final<<<1, 256, 0, stream>>>(loss, meta, out);
}

// Round 2
// 123.730 us; speedup vs baseline: 2.3484x; 2.3484x over previous
//
#include <hip/hip_runtime.h>
#include <hip/hip_bf16.h>
#include <math.h>

#define BB 4
#define PP 4096
#define HH 256
#define INV_T (1.0f/0.07f)

typedef __attribute__((ext_vector_type(8))) short bf16x8;
typedef __attribute__((ext_vector_type(4))) float f32x4;

__device__ __forceinline__ float waveReduceSum(float v){
  #pragma unroll
  for (int off = 32; off; off >>= 1) v += __shfl_xor(v, off);
  return v;
}

__device__ __forceinline__ unsigned short f2bf(float x){
  union { float f; unsigned u; } v; v.f = x;
  unsigned r = v.u + 0x7FFFu + ((v.u >> 16) & 1u);   // RNE
  return (unsigned short)(r >> 16);
}

// ---------------- K1: deterministic compaction ----------------
__global__ void k_compact(const int* __restrict__ labels, int* __restrict__ meta,
                          int* __restrict__ posIdx, int* __restrict__ negIdx){
  int b = blockIdx.x;
  const int* lab = labels + b * PP;
  __shared__ int wP[4], wN[4], wV[4];
  __shared__ int basePos, baseNeg, baseVal;
  int tid = threadIdx.x, wave = tid >> 6, lane = tid & 63;
  if (tid == 0){ basePos = 0; baseNeg = 0; baseVal = 0; }
  __syncthreads();
  for (int c = 0; c < PP; c += 256){
    int p = c + tid;
    int l = lab[p];
    bool isP = (l == 1), isN = (l == 0), isV = (l != -100);
    unsigned long long bP = __ballot(isP), bN = __ballot(isN), bV = __ballot(isV);
    unsigned long long lt = (1ull << lane) - 1ull;
    if (lane == 0){ wP[wave] = __popcll(bP); wN[wave] = __popcll(bN); wV[wave] = __popcll(bV); }
    __syncthreads();
    int offP = 0, offN = 0;
    for (int w = 0; w < wave; w++){ offP += wP[w]; offN += wN[w]; }
    if (isP) posIdx[b*PP + basePos + offP + __popcll(bP & lt)] = p;
    if (isN) negIdx[b*PP + baseNeg + offN + __popcll(bN & lt)] = p;
    __syncthreads();
    if (tid == 0){
      basePos += wP[0] + wP[1] + wP[2] + wP[3];
      baseNeg += wN[0] + wN[1] + wN[2] + wN[3];
      baseVal += wV[0] + wV[1] + wV[2] + wV[3];
    }
    __syncthreads();
  }
  if (tid == 0){
    int Np = basePos, Nn = baseNeg, nv = baseVal;
    meta[b*4+0] = Np;
    meta[b*4+1] = Nn;
    meta[b*4+2] = (nv >= 2 && Np > 0 && Nn > 0) ? 1 : 0;
    meta[b*4+3] = nv;
  }
}

// ---------------- K2: normalize -> bf16 compacted rows; diag in fp32 ----------------
// wave-per-row. first half of blocks: positive rows (Gpos + diag); second: negative rows (Eneg)
__global__ void k_norm(const float* __restrict__ greek, const float* __restrict__ english,
                       const int* __restrict__ meta, const int* __restrict__ posIdx,
                       const int* __restrict__ negIdx,
                       unsigned short* __restrict__ Gpos, unsigned short* __restrict__ Eneg,
                       float* __restrict__ diag){
  int tid = threadIdx.x, wave = tid >> 6, lane = tid & 63;
  int gb = blockIdx.x;
  const int HALF = BB * PP / 4;      // blocks per half
  bool isPos = gb < HALF;
  int rowBase = (gb % HALF) * 4 + wave;    // [0, B*P)
  int b = rowBase / PP;
  int i = rowBase % PP;
  int Np = meta[b*4+0], Nn = meta[b*4+1];

  if (isPos){
    if (i >= Np) return;
    int p = posIdx[b*PP + i];
    size_t base = ((size_t)b * PP + p) * HH + lane * 4;
    float4 g4 = *reinterpret_cast<const float4*>(greek + base);
    float ssg = waveReduceSum(g4.x*g4.x + g4.y*g4.y + g4.z*g4.z + g4.w*g4.w);
    float gs = 1.0f / fmaxf(sqrtf(ssg), 1e-12f);
    float gnx = g4.x*gs, gny = g4.y*gs, gnz = g4.z*gs, gnw = g4.w*gs;
    ushort4 go; go.x = f2bf(gnx); go.y = f2bf(gny); go.z = f2bf(gnz); go.w = f2bf(gnw);
    *reinterpret_cast<ushort4*>(Gpos + ((size_t)b*PP + i)*HH + lane*4) = go;
    float4 e4 = *reinterpret_cast<const float4*>(english + base);
    float sse = waveReduceSum(e4.x*e4.x + e4.y*e4.y + e4.z*e4.z + e4.w*e4.w);
    float es = 1.0f / fmaxf(sqrtf(sse), 1e-12f);
    float d = waveReduceSum((gnx*e4.x + gny*e4.y + gnz*e4.z + gnw*e4.w) * es);
    if (lane == 0) diag[b*PP + i] = d;
  } else {
    if (i >= Nn) return;
    int q = negIdx[b*PP + i];
    size_t base = ((size_t)b * PP + q) * HH + lane * 4;
    float4 e4 = *reinterpret_cast<const float4*>(english + base);
    float sse = waveReduceSum(e4.x*e4.x + e4.y*e4.y + e4.z*e4.z + e4.w*e4.w);
    float es = 1.0f / fmaxf(sqrtf(sse), 1e-12f);
    ushort4 eo; eo.x = f2bf(e4.x*es); eo.y = f2bf(e4.y*es); eo.z = f2bf(e4.z*es); eo.w = f2bf(e4.w*es);
    *reinterpret_cast<ushort4*>(Eneg + ((size_t)b*PP + i)*HH + lane*4) = eo;
  }
}

// ---------------- K3: MFMA sim + sum(exp) per row ----------------
// block = 16 pos rows; 4 waves split the neg col-tiles (16 cols each).
// Per wave: A-frags (16 rows) held in regs; per col-tile 8 bf16x8 B-frags + 8 MFMAs.
// No online max needed: |logit| <= ~14.3, exp in [6e-7, 1.6e6] -> fp32-safe.
__global__ void k_loss(const unsigned short* __restrict__ Gpos,
                       const unsigned short* __restrict__ Eneg,
                       const float* __restrict__ diag, const int* __restrict__ meta,
                       float* __restrict__ loss){
  int b = blockIdx.y;
  int i0 = blockIdx.x * 16;
  int tid = threadIdx.x;
  int Np = meta[b*4+0], Nn = meta[b*4+1], ok = meta[b*4+2];
  if (!ok || i0 >= Np){
    if (tid < 16) loss[b*PP + i0 + tid] = 0.0f;
    return;
  }
  int wave = tid >> 6, lane = tid & 63;
  int lo16 = lane & 15, hi4 = lane >> 4;

  // A fragments: row = lane&15, k = kk*32 + (lane>>4)*8 + j
  const unsigned short* G = Gpos + ((size_t)b*PP + i0) * HH;
  bool rowOK = (i0 + lo16) < Np;
  const unsigned short* gRow = G + (size_t)lo16 * HH + hi4 * 8;
  bf16x8 a[8];
  #pragma unroll
  for (int kk = 0; kk < 8; kk++){
    bf16x8 z = {0,0,0,0,0,0,0,0};
    a[kk] = rowOK ? *reinterpret_cast<const bf16x8*>(gRow + kk*32) : z;
  }

  const unsigned short* E = Eneg + (size_t)b * PP * HH;
  int NT = (Nn + 15) >> 4;
  float s[4] = {0.f, 0.f, 0.f, 0.f};

  for (int jt = wave; jt < NT; jt += 8){
    int jt2 = jt + 4;
    bool has2 = (jt2 < NT);          // wave-uniform

    int col1 = jt*16 + lo16;
    bool c1ok = col1 < Nn;
    const unsigned short* eRow1 = E + (size_t)col1 * HH + hi4 * 8;
    bf16x8 b1[8];
    #pragma unroll
    for (int kk = 0; kk < 8; kk++){
      bf16x8 z = {0,0,0,0,0,0,0,0};
      b1[kk] = c1ok ? *reinterpret_cast<const bf16x8*>(eRow1 + kk*32) : z;
    }
    bf16x8 b2[8];
    int col2 = jt2*16 + lo16;
    bool c2ok = has2 && (col2 < Nn);
    if (has2){
      const unsigned short* eRow2 = E + (size_t)col2 * HH + hi4 * 8;
      #pragma unroll
      for (int kk = 0; kk < 8; kk++){
        bf16x8 z = {0,0,0,0,0,0,0,0};
        b2[kk] = c2ok ? *reinterpret_cast<const bf16x8*>(eRow2 + kk*32) : z;
      }
    }

    f32x4 c1 = {0.f,0.f,0.f,0.f}, c2 = {0.f,0.f,0.f,0.f};
    #pragma unroll
    for (int kk = 0; kk < 8; kk++){
      c1 = __builtin_amdgcn_mfma_f32_16x16x32_bf16(a[kk], b1[kk], c1, 0, 0, 0);
      if (has2) c2 = __builtin_amdgcn_mfma_f32_16x16x32_bf16(a[kk], b2[kk], c2, 0, 0, 0);
    }
    #pragma unroll
    for (int r = 0; r < 4; r++){
      float l1 = c1[r] * INV_T;
      s[r] += c1ok ? __expf(l1) : 0.0f;
    }
    if (has2){
      #pragma unroll
      for (int r = 0; r < 4; r++){
        float l2 = c2[r] * INV_T;
        s[r] += c2ok ? __expf(l2) : 0.0f;
      }
    }
  }

  // sum across the 16 lanes sharing the same output rows
  #pragma unroll
  for (int off = 1; off < 16; off <<= 1){
    #pragma unroll
    for (int r = 0; r < 4; r++) s[r] += __shfl_xor(s[r], off);
  }
  // lane&15==0 holds rows hi4*4 + r
  __shared__ float sLds[4][16];
  if (lo16 == 0){
    #pragma unroll
    for (int r = 0; r < 4; r++) sLds[wave][hi4*4 + r] = s[r];
  }
  __syncthreads();
  if (tid < 16){
    int i = i0 + tid;
    float S = sLds[0][tid] + sLds[1][tid] + sLds[2][tid] + sLds[3][tid];
    float out = 0.0f;
    if (i < Np){
      float dl = diag[b*PP + i] * INV_T;
      out = logf(S + expf(dl)) - dl;
    }
    loss[b*PP + i] = out;
  }
}

// ---------------- K4: deterministic final reduce ----------------
__global__ void k_final(const float* __restrict__ loss, const int* __restrict__ meta,
                        float* __restrict__ out){
  __shared__ float lds[4];
  int tid = threadIdx.x;
  float v = 0.0f;
  for (int idx = tid; idx < BB*PP; idx += 256) v += loss[idx];
  #pragma unroll
  for (int off = 32; off; off >>= 1) v += __shfl_xor(v, off);
  int wave = tid >> 6;
  if ((tid & 63) == 0) lds[wave] = v;
  __syncthreads();
  if (tid == 0){
    float total = lds[0] + lds[1] + lds[2] + lds[3];
    int count = 0;
    for (int b = 0; b < BB; b++) if (meta[b*4+2]) count += meta[b*4+0];
    out[0] = (count == 0) ? 0.0f : total / (float)count;
  }
}

extern "C" void kernel_launch(void* const* d_in, const int* in_sizes, int n_in,
                              void* d_out, int out_size, void* d_ws, size_t ws_size,
                              hipStream_t stream){
  const float* greek   = (const float*)d_in[0];
  const float* english = (const float*)d_in[1];
  const int*   labels  = (const int*)d_in[2];
  float* out = (float*)d_out;

  char* ws = (char*)d_ws;
  size_t off = 0;
  unsigned short* Gpos = (unsigned short*)(ws + off); off += (size_t)BB*PP*HH*sizeof(unsigned short); // 8MB
  unsigned short* Eneg = (unsigned short*)(ws + off); off += (size_t)BB*PP*HH*sizeof(unsigned short); // 8MB
  float* diag   = (float*)(ws + off); off += (size_t)BB*PP*sizeof(float);
  float* loss   = (float*)(ws + off); off += (size_t)BB*PP*sizeof(float);
  int*   posIdx = (int*)(ws + off);   off += (size_t)BB*PP*sizeof(int);
  int*   negIdx = (int*)(ws + off);   off += (size_t)BB*PP*sizeof(int);
  int*   meta   = (int*)(ws + off);   off += 64;

  k_compact<<<BB, 256, 0, stream>>>(labels, meta, posIdx, negIdx);
  k_norm<<<2*BB*PP/4, 256, 0, stream>>>(greek, english, meta, posIdx, negIdx,
                                        Gpos, Eneg, diag);
  dim3 g3(PP/16, BB);
  k_loss<<<g3, 256, 0, stream>>>(Gpos, Eneg, diag, meta, loss);
  k_final<<<1, 256, 0, stream>>>(loss, meta, out);
}

// Round 3
// 78.783 us; speedup vs baseline: 3.6882x; 1.5705x over previous
//
#include <hip/hip_runtime.h>
#include <hip/hip_bf16.h>
#include <math.h>

#define BB 4
#define PP 4096
#define HH 256
#define INV_T (1.0f/0.07f)
#define JSPLIT 8

typedef __attribute__((ext_vector_type(8))) short bf16x8;
typedef __attribute__((ext_vector_type(4))) float f32x4;

__device__ __forceinline__ float waveReduceSum(float v){
  #pragma unroll
  for (int off = 32; off; off >>= 1) v += __shfl_xor(v, off);
  return v;
}

__device__ __forceinline__ unsigned short f2bf(float x){
  union { float f; unsigned u; } v; v.f = x;
  unsigned r = v.u + 0x7FFFu + ((v.u >> 16) & 1u);   // RNE
  return (unsigned short)(r >> 16);
}

// ---------------- K1: deterministic compaction ----------------
__global__ void k_compact(const int* __restrict__ labels, int* __restrict__ meta,
                          int* __restrict__ posIdx, int* __restrict__ negIdx){
  int b = blockIdx.x;
  const int* lab = labels + b * PP;
  __shared__ int wP[4], wN[4], wV[4];
  __shared__ int basePos, baseNeg, baseVal;
  int tid = threadIdx.x, wave = tid >> 6, lane = tid & 63;
  if (tid == 0){ basePos = 0; baseNeg = 0; baseVal = 0; }
  __syncthreads();
  for (int c = 0; c < PP; c += 256){
    int p = c + tid;
    int l = lab[p];
    bool isP = (l == 1), isN = (l == 0), isV = (l != -100);
    unsigned long long bP = __ballot(isP), bN = __ballot(isN), bV = __ballot(isV);
    unsigned long long lt = (1ull << lane) - 1ull;
    if (lane == 0){ wP[wave] = __popcll(bP); wN[wave] = __popcll(bN); wV[wave] = __popcll(bV); }
    __syncthreads();
    int offP = 0, offN = 0;
    for (int w = 0; w < wave; w++){ offP += wP[w]; offN += wN[w]; }
    if (isP) posIdx[b*PP + basePos + offP + __popcll(bP & lt)] = p;
    if (isN) negIdx[b*PP + baseNeg + offN + __popcll(bN & lt)] = p;
    __syncthreads();
    if (tid == 0){
      basePos += wP[0] + wP[1] + wP[2] + wP[3];
      baseNeg += wN[0] + wN[1] + wN[2] + wN[3];
      baseVal += wV[0] + wV[1] + wV[2] + wV[3];
    }
    __syncthreads();
  }
  if (tid == 0){
    int Np = basePos, Nn = baseNeg, nv = baseVal;
    meta[b*4+0] = Np;
    meta[b*4+1] = Nn;
    meta[b*4+2] = (nv >= 2 && Np > 0 && Nn > 0) ? 1 : 0;
    meta[b*4+3] = nv;
  }
}

// ---------------- K2: normalize -> bf16 compacted rows; diag in fp32 ----------------
__global__ void k_norm(const float* __restrict__ greek, const float* __restrict__ english,
                       const int* __restrict__ meta, const int* __restrict__ posIdx,
                       const int* __restrict__ negIdx,
                       unsigned short* __restrict__ Gpos, unsigned short* __restrict__ Eneg,
                       float* __restrict__ diag){
  int tid = threadIdx.x, wave = tid >> 6, lane = tid & 63;
  int gb = blockIdx.x;
  const int HALF = BB * PP / 4;      // blocks per half
  bool isPos = gb < HALF;
  int rowBase = (gb % HALF) * 4 + wave;    // [0, B*P)
  int b = rowBase / PP;
  int i = rowBase % PP;
  int Np = meta[b*4+0], Nn = meta[b*4+1];

  if (isPos){
    if (i >= Np) return;
    int p = posIdx[b*PP + i];
    size_t base = ((size_t)b * PP + p) * HH + lane * 4;
    float4 g4 = *reinterpret_cast<const float4*>(greek + base);
    float ssg = waveReduceSum(g4.x*g4.x + g4.y*g4.y + g4.z*g4.z + g4.w*g4.w);
    float gs = 1.0f / fmaxf(sqrtf(ssg), 1e-12f);
    float gnx = g4.x*gs, gny = g4.y*gs, gnz = g4.z*gs, gnw = g4.w*gs;
    ushort4 go; go.x = f2bf(gnx); go.y = f2bf(gny); go.z = f2bf(gnz); go.w = f2bf(gnw);
    *reinterpret_cast<ushort4*>(Gpos + ((size_t)b*PP + i)*HH + lane*4) = go;
    float4 e4 = *reinterpret_cast<const float4*>(english + base);
    float sse = waveReduceSum(e4.x*e4.x + e4.y*e4.y + e4.z*e4.z + e4.w*e4.w);
    float es = 1.0f / fmaxf(sqrtf(sse), 1e-12f);
    float d = waveReduceSum((gnx*e4.x + gny*e4.y + gnz*e4.z + gnw*e4.w) * es);
    if (lane == 0) diag[b*PP + i] = d;
  } else {
    if (i >= Nn) return;
    int q = negIdx[b*PP + i];
    size_t base = ((size_t)b * PP + q) * HH + lane * 4;
    float4 e4 = *reinterpret_cast<const float4*>(english + base);
    float sse = waveReduceSum(e4.x*e4.x + e4.y*e4.y + e4.z*e4.z + e4.w*e4.w);
    float es = 1.0f / fmaxf(sqrtf(sse), 1e-12f);
    ushort4 eo; eo.x = f2bf(e4.x*es); eo.y = f2bf(e4.y*es); eo.z = f2bf(e4.z*es); eo.w = f2bf(e4.w*es);
    *reinterpret_cast<ushort4*>(Eneg + ((size_t)b*PP + i)*HH + lane*4) = eo;
  }
}

// ---------------- K3: MFMA partial exp-sums, j-split across blocks ----------------
// grid (PP/64, BB, JSPLIT). Block = 64 pos rows; wave w owns row-tile w (A in regs)
// and sweeps this block's col-tile chunk -> all 4 waves share B lines (L1 reuse).
// No online max: |logit| <= 14.3 -> exp in fp32-safe range; partials additive over j.
__global__ void k_loss(const unsigned short* __restrict__ Gpos,
                       const unsigned short* __restrict__ Eneg,
                       const int* __restrict__ meta,
                       float* __restrict__ Spart){
  int b = blockIdx.y, chunk = blockIdx.z;
  int Np = meta[b*4+0], Nn = meta[b*4+1], ok = meta[b*4+2];
  int i0 = blockIdx.x * 64;
  if (!ok || i0 >= Np) return;
  int tid = threadIdx.x, wave = tid >> 6, lane = tid & 63;
  int lo16 = lane & 15, hi4 = lane >> 4;
  int iw = i0 + wave * 16;                 // this wave's row-tile base (< PP always)
  int NT = (Nn + 15) >> 4;
  int TPC = (NT + JSPLIT - 1) / JSPLIT;
  int t0 = chunk * TPC, t1 = min(NT, t0 + TPC);

  // A frags: row = lane&15, k = kk*32 + (lane>>4)*8 + j
  bool rowOK = (iw + lo16) < Np;
  const unsigned short* gRow = Gpos + ((size_t)b*PP + iw + lo16) * HH + hi4 * 8;
  bf16x8 a[8];
  #pragma unroll
  for (int kk = 0; kk < 8; kk++){
    bf16x8 z = {0,0,0,0,0,0,0,0};
    a[kk] = rowOK ? *reinterpret_cast<const bf16x8*>(gRow + kk*32) : z;
  }

  const unsigned short* E = Eneg + (size_t)b * PP * HH;
  float s[4] = {0.f, 0.f, 0.f, 0.f};

  for (int jt = t0; jt < t1; jt += 2){
    bool has2 = (jt + 1 < t1);             // wave-uniform
    int col1 = jt*16 + lo16;
    bool c1ok = col1 < Nn;
    const unsigned short* eRow1 = E + (size_t)col1 * HH + hi4 * 8;
    bf16x8 b1[8];
    #pragma unroll
    for (int kk = 0; kk < 8; kk++){
      bf16x8 z = {0,0,0,0,0,0,0,0};
      b1[kk] = c1ok ? *reinterpret_cast<const bf16x8*>(eRow1 + kk*32) : z;
    }
    bf16x8 b2[8];
    int col2 = (jt+1)*16 + lo16;
    bool c2ok = has2 && (col2 < Nn);
    if (has2){
      const unsigned short* eRow2 = E + (size_t)col2 * HH + hi4 * 8;
      #pragma unroll
      for (int kk = 0; kk < 8; kk++){
        bf16x8 z = {0,0,0,0,0,0,0,0};
        b2[kk] = c2ok ? *reinterpret_cast<const bf16x8*>(eRow2 + kk*32) : z;
      }
    }
    f32x4 c1 = {0.f,0.f,0.f,0.f}, c2 = {0.f,0.f,0.f,0.f};
    #pragma unroll
    for (int kk = 0; kk < 8; kk++){
      c1 = __builtin_amdgcn_mfma_f32_16x16x32_bf16(a[kk], b1[kk], c1, 0, 0, 0);
      if (has2) c2 = __builtin_amdgcn_mfma_f32_16x16x32_bf16(a[kk], b2[kk], c2, 0, 0, 0);
    }
    #pragma unroll
    for (int r = 0; r < 4; r++)
      s[r] += c1ok ? __expf(c1[r] * INV_T) : 0.0f;
    if (has2){
      #pragma unroll
      for (int r = 0; r < 4; r++)
        s[r] += c2ok ? __expf(c2[r] * INV_T) : 0.0f;
    }
  }

  // sum across the 16 lanes (col groups); D layout: row = hi4*4 + r, col = lo16
  #pragma unroll
  for (int off = 1; off < 16; off <<= 1){
    #pragma unroll
    for (int r = 0; r < 4; r++) s[r] += __shfl_xor(s[r], off);
  }
  if (lo16 == 0){
    #pragma unroll
    for (int r = 0; r < 4; r++){
      int i = iw + hi4*4 + r;                       // < i0+64 <= PP
      Spart[(((size_t)b*PP + i) << 3) + chunk] = s[r];
    }
  }
}

// ---------------- K4: fold partials -> per-row loss -> mean ----------------
__global__ void k_final(const float* __restrict__ Spart, const float* __restrict__ diag,
                        const int* __restrict__ meta, float* __restrict__ out){
  __shared__ float lds[16];
  int tid = threadIdx.x;
  int np[BB], okk[BB];
  #pragma unroll
  for (int b = 0; b < BB; b++){ np[b] = meta[b*4+0]; okk[b] = meta[b*4+2]; }
  float tot = 0.0f;
  for (int idx = tid; idx < BB*PP; idx += 1024){
    int b = idx >> 12, i = idx & (PP-1);
    if (!okk[b] || i >= np[b]) continue;
    const float4* p = reinterpret_cast<const float4*>(Spart + ((size_t)idx << 3));
    float4 p0 = p[0], p1 = p[1];
    float S = ((p0.x+p0.y)+(p0.z+p0.w)) + ((p1.x+p1.y)+(p1.z+p1.w));
    float dl = diag[idx] * INV_T;
    tot += logf(S + expf(dl)) - dl;
  }
  #pragma unroll
  for (int off = 32; off; off >>= 1) tot += __shfl_xor(tot, off);
  int wave = tid >> 6;
  if ((tid & 63) == 0) lds[wave] = tot;
  __syncthreads();
  if (tid == 0){
    float total = 0.0f;
    #pragma unroll
    for (int w = 0; w < 16; w++) total += lds[w];
    int count = 0;
    #pragma unroll
    for (int b = 0; b < BB; b++) if (okk[b]) count += np[b];
    out[0] = (count == 0) ? 0.0f : total / (float)count;
  }
}

extern "C" void kernel_launch(void* const* d_in, const int* in_sizes, int n_in,
                              void* d_out, int out_size, void* d_ws, size_t ws_size,
                              hipStream_t stream){
  const float* greek   = (const float*)d_in[0];
  const float* english = (const float*)d_in[1];
  const int*   labels  = (const int*)d_in[2];
  float* out = (float*)d_out;

  char* ws = (char*)d_ws;
  size_t off = 0;
  unsigned short* Gpos = (unsigned short*)(ws + off); off += (size_t)BB*PP*HH*sizeof(unsigned short); // 8MB
  unsigned short* Eneg = (unsigned short*)(ws + off); off += (size_t)BB*PP*HH*sizeof(unsigned short); // 8MB
  float* Spart  = (float*)(ws + off); off += (size_t)BB*PP*JSPLIT*sizeof(float);  // 512KB
  float* diag   = (float*)(ws + off); off += (size_t)BB*PP*sizeof(float);
  int*   posIdx = (int*)(ws + off);   off += (size_t)BB*PP*sizeof(int);
  int*   negIdx = (int*)(ws + off);   off += (size_t)BB*PP*sizeof(int);
  int*   meta   = (int*)(ws + off);   off += 64;

  k_compact<<<BB, 256, 0, stream>>>(labels, meta, posIdx, negIdx);
  k_norm<<<2*BB*PP/4, 256, 0, stream>>>(greek, english, meta, posIdx, negIdx,
                                        Gpos, Eneg, diag);
  dim3 g3(PP/64, BB, JSPLIT);
  k_loss<<<g3, 256, 0, stream>>>(Gpos, Eneg, meta, Spart);
  k_final<<<1, 1024, 0, stream>>>(Spart, diag, meta, out);
}

// Round 4
// 47.267 us; speedup vs baseline: 6.1473x; 1.6668x over previous
//
#include <hip/hip_runtime.h>
#include <hip/hip_bf16.h>
#include <math.h>

#define BB 4
#define PP 4096
#define HH 256
#define INV_T (1.0f/0.07f)
#define JSPLIT 8
#define NTILES (PP/16)          // max 16-row/col tiles per batch
#define TILE_BYTES (16*HH*2)    // 8192 B per fragment-ready tile

typedef __attribute__((ext_vector_type(8))) short bf16x8;
typedef __attribute__((ext_vector_type(4))) float f32x4;

__device__ __forceinline__ float waveReduceSum(float v){
  #pragma unroll
  for (int off = 32; off; off >>= 1) v += __shfl_xor(v, off);
  return v;
}

__device__ __forceinline__ unsigned short f2bf(float x){
  union { float f; unsigned u; } v; v.f = x;
  unsigned r = v.u + 0x7FFFu + ((v.u >> 16) & 1u);   // RNE
  return (unsigned short)(r >> 16);
}

__device__ __forceinline__ void gload_lds16(const void* g, void* l){
  __builtin_amdgcn_global_load_lds(
      (const __attribute__((address_space(1))) unsigned int*)g,
      (__attribute__((address_space(3))) unsigned int*)l, 16, 0, 0);
}

// ---------------- K1: deterministic compaction ----------------
__global__ void k_compact(const int* __restrict__ labels, int* __restrict__ meta,
                          int* __restrict__ posIdx, int* __restrict__ negIdx){
  int b = blockIdx.x;
  const int* lab = labels + b * PP;
  __shared__ int wP[4], wN[4], wV[4];
  __shared__ int basePos, baseNeg, baseVal;
  int tid = threadIdx.x, wave = tid >> 6, lane = tid & 63;
  if (tid == 0){ basePos = 0; baseNeg = 0; baseVal = 0; }
  __syncthreads();
  for (int c = 0; c < PP; c += 256){
    int p = c + tid;
    int l = lab[p];
    bool isP = (l == 1), isN = (l == 0), isV = (l != -100);
    unsigned long long bP = __ballot(isP), bN = __ballot(isN), bV = __ballot(isV);
    unsigned long long lt = (1ull << lane) - 1ull;
    if (lane == 0){ wP[wave] = __popcll(bP); wN[wave] = __popcll(bN); wV[wave] = __popcll(bV); }
    __syncthreads();
    int offP = 0, offN = 0;
    for (int w = 0; w < wave; w++){ offP += wP[w]; offN += wN[w]; }
    if (isP) posIdx[b*PP + basePos + offP + __popcll(bP & lt)] = p;
    if (isN) negIdx[b*PP + baseNeg + offN + __popcll(bN & lt)] = p;
    __syncthreads();
    if (tid == 0){
      basePos += wP[0] + wP[1] + wP[2] + wP[3];
      baseNeg += wN[0] + wN[1] + wN[2] + wN[3];
      baseVal += wV[0] + wV[1] + wV[2] + wV[3];
    }
    __syncthreads();
  }
  if (tid == 0){
    int Np = basePos, Nn = baseNeg, nv = baseVal;
    meta[b*4+0] = Np;
    meta[b*4+1] = Nn;
    meta[b*4+2] = (nv >= 2 && Np > 0 && Nn > 0) ? 1 : 0;
    meta[b*4+3] = nv;
  }
}

// ---------------- K2: normalize -> FRAGMENT-READY bf16 tiles ----------------
// Fragment-ready layout per 16-row tile: byte = tile*8192 + kk*1024 + slot*16,
// slot = (row&15) + hi4*16, covering k = kk*32 + hi4*8 + j (j=0..7).
// Wave handles one row: lane holds k=lane*4..+3; pairs of lanes merge to one
// 16B chunk via shfl; even lanes store. Tail rows [N, ceil16(N)) zero-filled.
__global__ void k_norm(const float* __restrict__ greek, const float* __restrict__ english,
                       const int* __restrict__ meta, const int* __restrict__ posIdx,
                       const int* __restrict__ negIdx,
                       unsigned short* __restrict__ GposF, unsigned short* __restrict__ EnegF,
                       float* __restrict__ diag){
  int tid = threadIdx.x, wave = tid >> 6, lane = tid & 63;
  int gb = blockIdx.x;
  const int HALF = BB * PP / 4;
  bool isPos = gb < HALF;
  int rowBase = (gb % HALF) * 4 + wave;
  int b = rowBase / PP;
  int i = rowBase % PP;
  int Np = meta[b*4+0], Nn = meta[b*4+1];
  int Ncount = isPos ? Np : Nn;
  unsigned short* buf = isPos ? GposF : EnegF;
  char* dst = (char*)buf + ((size_t)b*NTILES + (i>>4))*TILE_BYTES
            + (lane>>3)*1024 + (((i&15) + ((lane>>1)&3)*16) << 4);

  if (i >= Ncount){
    if (i < ((Ncount + 15) & ~15) && !(lane & 1))
      *(uint4*)dst = make_uint4(0u,0u,0u,0u);
    return;
  }
  const int* idx = isPos ? posIdx : negIdx;
  int p = idx[b*PP + i];
  size_t base = ((size_t)b * PP + p) * HH + lane * 4;

  if (isPos){
    float4 g4 = *reinterpret_cast<const float4*>(greek + base);
    float ssg = waveReduceSum(g4.x*g4.x + g4.y*g4.y + g4.z*g4.z + g4.w*g4.w);
    float gs = 1.0f / fmaxf(sqrtf(ssg), 1e-12f);
    float gx = g4.x*gs, gy = g4.y*gs, gz = g4.z*gs, gw = g4.w*gs;
    unsigned u0 = (unsigned)f2bf(gx) | ((unsigned)f2bf(gy) << 16);
    unsigned u1 = (unsigned)f2bf(gz) | ((unsigned)f2bf(gw) << 16);
    unsigned o0 = __shfl_xor(u0, 1), o1 = __shfl_xor(u1, 1);
    if (!(lane & 1)) *(uint4*)dst = make_uint4(u0, u1, o0, o1);
    float4 e4 = *reinterpret_cast<const float4*>(english + base);
    float sse = waveReduceSum(e4.x*e4.x + e4.y*e4.y + e4.z*e4.z + e4.w*e4.w);
    float es = 1.0f / fmaxf(sqrtf(sse), 1e-12f);
    float d = waveReduceSum((gx*e4.x + gy*e4.y + gz*e4.z + gw*e4.w) * es);
    if (lane == 0) diag[b*PP + i] = d;
  } else {
    float4 e4 = *reinterpret_cast<const float4*>(english + base);
    float sse = waveReduceSum(e4.x*e4.x + e4.y*e4.y + e4.z*e4.z + e4.w*e4.w);
    float es = 1.0f / fmaxf(sqrtf(sse), 1e-12f);
    unsigned u0 = (unsigned)f2bf(e4.x*es) | ((unsigned)f2bf(e4.y*es) << 16);
    unsigned u1 = (unsigned)f2bf(e4.z*es) | ((unsigned)f2bf(e4.w*es) << 16);
    unsigned o0 = __shfl_xor(u0, 1), o1 = __shfl_xor(u1, 1);
    if (!(lane & 1)) *(uint4*)dst = make_uint4(u0, u1, o0, o1);
  }
}

// ---------------- K3: MFMA exp-sums, LDS double-buffered B pipeline ----------------
// grid (PP/64, BB, JSPLIT), block = 4 waves x 16-row tiles (A in regs, frag-ready
// coalesced load). B-tiles staged to LDS via global_load_lds (linear dest, no
// VGPR round-trip), double-buffered: stage(next); ds_read+MFMA+exp(cur); barrier.
__global__ void __launch_bounds__(256, 4)
k_loss(const unsigned short* __restrict__ GposF,
       const unsigned short* __restrict__ EnegF,
       const int* __restrict__ meta,
       float* __restrict__ Spart){
  int b = blockIdx.y, chunk = blockIdx.z;
  int Np = meta[b*4+0], Nn = meta[b*4+1], ok = meta[b*4+2];
  int i0 = blockIdx.x * 64;
  if (!ok || i0 >= Np) return;
  int tid = threadIdx.x, wave = tid >> 6, lane = tid & 63;
  int lo16 = lane & 15, hi4 = lane >> 4;
  int NT = (Nn + 15) >> 4;
  int TPC = (NT + JSPLIT - 1) / JSPLIT;
  int t0 = chunk * TPC, t1 = min(NT, t0 + TPC);

  __shared__ __align__(16) char Bs[2][TILE_BYTES];   // 16 KB double buffer
  __shared__ float sLds[4][16];

  // A fragments (one-time, fully coalesced)
  const char* AF = (const char*)GposF + ((size_t)b*NTILES + (i0 >> 4) + wave) * TILE_BYTES;
  bf16x8 a[8];
  #pragma unroll
  for (int kk = 0; kk < 8; kk++)
    a[kk] = *reinterpret_cast<const bf16x8*>(AF + kk*1024 + (lane << 4));

  const char* EF = (const char*)EnegF + (size_t)b * NTILES * TILE_BYTES;
  float s[4] = {0.f, 0.f, 0.f, 0.f};

  if (t0 < t1){
    // prologue: stage first tile (wave w fills its 2KB quarter)
    {
      const char* src = EF + (size_t)t0*TILE_BYTES + (wave << 11) + (lane << 4);
      char* dstl = &Bs[0][wave << 11];
      gload_lds16(src, dstl);
      gload_lds16(src + 1024, dstl + 1024);
    }
    __syncthreads();   // drains vmcnt: tile t0 resident
    int cur = 0;
    for (int t = t0; t < t1; t++){
      int nxt = (t + 1 < t1) ? t + 1 : t0;   // dummy re-stage on last iter
      const char* src = EF + (size_t)nxt*TILE_BYTES + (wave << 11) + (lane << 4);
      char* dstl = &Bs[cur ^ 1][wave << 11];
      gload_lds16(src, dstl);
      gload_lds16(src + 1024, dstl + 1024);

      // compute current tile from LDS
      const char* Bt = &Bs[cur][0];
      f32x4 c = {0.f, 0.f, 0.f, 0.f};
      #pragma unroll
      for (int kk = 0; kk < 8; kk++){
        bf16x8 bv = *reinterpret_cast<const bf16x8*>(Bt + kk*1024 + (lane << 4));
        c = __builtin_amdgcn_mfma_f32_16x16x32_bf16(a[kk], bv, c, 0, 0, 0);
      }
      bool cok = (t*16 + lo16) < Nn;
      #pragma unroll
      for (int r = 0; r < 4; r++)
        s[r] += cok ? __expf(c[r] * INV_T) : 0.0f;

      __syncthreads();  // drains staged next-tile + all waves done with cur
      cur ^= 1;
    }
  }

  // reduce across the 16 lanes sharing output rows (D: col=lane&15, row=hi4*4+r)
  #pragma unroll
  for (int off = 1; off < 16; off <<= 1){
    #pragma unroll
    for (int r = 0; r < 4; r++) s[r] += __shfl_xor(s[r], off);
  }
  if (lo16 == 0){
    #pragma unroll
    for (int r = 0; r < 4; r++){
      int i = i0 + wave*16 + hi4*4 + r;
      Spart[(((size_t)b*PP + i) << 3) + chunk] = s[r];
    }
  }
}

// ---------------- K4: fold partials -> per-row loss -> mean ----------------
__global__ void k_final(const float* __restrict__ Spart, const float* __restrict__ diag,
                        const int* __restrict__ meta, float* __restrict__ out){
  __shared__ float lds[16];
  int tid = threadIdx.x;
  int np[BB], okk[BB];
  #pragma unroll
  for (int b = 0; b < BB; b++){ np[b] = meta[b*4+0]; okk[b] = meta[b*4+2]; }
  float tot = 0.0f;
  for (int idx = tid; idx < BB*PP; idx += 1024){
    int b = idx >> 12, i = idx & (PP-1);
    if (!okk[b] || i >= np[b]) continue;
    const float4* p = reinterpret_cast<const float4*>(Spart + ((size_t)idx << 3));
    float4 p0 = p[0], p1 = p[1];
    float S = ((p0.x+p0.y)+(p0.z+p0.w)) + ((p1.x+p1.y)+(p1.z+p1.w));
    float dl = diag[idx] * INV_T;
    tot += logf(S + expf(dl)) - dl;
  }
  #pragma unroll
  for (int off = 32; off; off >>= 1) tot += __shfl_xor(tot, off);
  int wave = tid >> 6;
  if ((tid & 63) == 0) lds[wave] = tot;
  __syncthreads();
  if (tid == 0){
    float total = 0.0f;
    #pragma unroll
    for (int w = 0; w < 16; w++) total += lds[w];
    int count = 0;
    #pragma unroll
    for (int b = 0; b < BB; b++) if (okk[b]) count += np[b];
    out[0] = (count == 0) ? 0.0f : total / (float)count;
  }
}

extern "C" void kernel_launch(void* const* d_in, const int* in_sizes, int n_in,
                              void* d_out, int out_size, void* d_ws, size_t ws_size,
                              hipStream_t stream){
  const float* greek   = (const float*)d_in[0];
  const float* english = (const float*)d_in[1];
  const int*   labels  = (const int*)d_in[2];
  float* out = (float*)d_out;

  char* ws = (char*)d_ws;
  size_t off = 0;
  unsigned short* GposF = (unsigned short*)(ws + off); off += (size_t)BB*NTILES*TILE_BYTES; // 8MB
  unsigned short* EnegF = (unsigned short*)(ws + off); off += (size_t)BB*NTILES*TILE_BYTES; // 8MB
  float* Spart  = (float*)(ws + off); off += (size_t)BB*PP*JSPLIT*sizeof(float);  // 512KB
  float* diag   = (float*)(ws + off); off += (size_t)BB*PP*sizeof(float);
  int*   posIdx = (int*)(ws + off);   off += (size_t)BB*PP*sizeof(int);
  int*   negIdx = (int*)(ws + off);   off += (size_t)BB*PP*sizeof(int);
  int*   meta   = (int*)(ws + off);   off += 64;

  k_compact<<<BB, 256, 0, stream>>>(labels, meta, posIdx, negIdx);
  k_norm<<<2*BB*PP/4, 256, 0, stream>>>(greek, english, meta, posIdx, negIdx,
                                        GposF, EnegF, diag);
  dim3 g3(PP/64, BB, JSPLIT);
  k_loss<<<g3, 256, 0, stream>>>(GposF, EnegF, meta, Spart);
  k_final<<<1, 1024, 0, stream>>>(Spart, diag, meta, out);
}

// Round 5
// 42.195 us; speedup vs baseline: 6.8863x; 1.1202x over previous
//
#include <hip/hip_runtime.h>
#include <hip/hip_bf16.h>
#include <math.h>

#define BB 4
#define PP 4096
#define HH 256
#define INV_T (1.0f/0.07f)
#define JSPLIT 8
#define NTILES (PP/16)          // max 16-row/col tiles per batch
#define TILE_BYTES (16*HH*2)    // 8192 B per fragment-ready tile

typedef __attribute__((ext_vector_type(8))) short bf16x8;
typedef __attribute__((ext_vector_type(4))) float f32x4;

#define WAITVM(n) asm volatile("s_waitcnt vmcnt(" #n ")" ::: "memory")

__device__ __forceinline__ float waveReduceSum(float v){
  #pragma unroll
  for (int off = 32; off; off >>= 1) v += __shfl_xor(v, off);
  return v;
}

__device__ __forceinline__ unsigned short f2bf(float x){
  union { float f; unsigned u; } v; v.f = x;
  unsigned r = v.u + 0x7FFFu + ((v.u >> 16) & 1u);   // RNE
  return (unsigned short)(r >> 16);
}

__device__ __forceinline__ void gload_lds16(const void* g, void* l){
  __builtin_amdgcn_global_load_lds(
      (const __attribute__((address_space(1))) unsigned int*)g,
      (__attribute__((address_space(3))) unsigned int*)l, 16, 0, 0);
}

// ---------------- K1: deterministic compaction ----------------
__global__ void k_compact(const int* __restrict__ labels, int* __restrict__ meta,
                          int* __restrict__ posIdx, int* __restrict__ negIdx){
  int b = blockIdx.x;
  const int* lab = labels + b * PP;
  __shared__ int wP[4], wN[4], wV[4];
  __shared__ int basePos, baseNeg, baseVal;
  int tid = threadIdx.x, wave = tid >> 6, lane = tid & 63;
  if (tid == 0){ basePos = 0; baseNeg = 0; baseVal = 0; }
  __syncthreads();
  for (int c = 0; c < PP; c += 256){
    int p = c + tid;
    int l = lab[p];
    bool isP = (l == 1), isN = (l == 0), isV = (l != -100);
    unsigned long long bP = __ballot(isP), bN = __ballot(isN), bV = __ballot(isV);
    unsigned long long lt = (1ull << lane) - 1ull;
    if (lane == 0){ wP[wave] = __popcll(bP); wN[wave] = __popcll(bN); wV[wave] = __popcll(bV); }
    __syncthreads();
    int offP = 0, offN = 0;
    for (int w = 0; w < wave; w++){ offP += wP[w]; offN += wN[w]; }
    if (isP) posIdx[b*PP + basePos + offP + __popcll(bP & lt)] = p;
    if (isN) negIdx[b*PP + baseNeg + offN + __popcll(bN & lt)] = p;
    __syncthreads();
    if (tid == 0){
      basePos += wP[0] + wP[1] + wP[2] + wP[3];
      baseNeg += wN[0] + wN[1] + wN[2] + wN[3];
      baseVal += wV[0] + wV[1] + wV[2] + wV[3];
    }
    __syncthreads();
  }
  if (tid == 0){
    int Np = basePos, Nn = baseNeg, nv = baseVal;
    meta[b*4+0] = Np;
    meta[b*4+1] = Nn;
    meta[b*4+2] = (nv >= 2 && Np > 0 && Nn > 0) ? 1 : 0;
    meta[b*4+3] = nv;
  }
}

// ---------------- K2: normalize -> FRAGMENT-READY bf16 tiles ----------------
__global__ void k_norm(const float* __restrict__ greek, const float* __restrict__ english,
                       const int* __restrict__ meta, const int* __restrict__ posIdx,
                       const int* __restrict__ negIdx,
                       unsigned short* __restrict__ GposF, unsigned short* __restrict__ EnegF,
                       float* __restrict__ diag){
  int tid = threadIdx.x, wave = tid >> 6, lane = tid & 63;
  int gb = blockIdx.x;
  const int HALF = BB * PP / 4;
  bool isPos = gb < HALF;
  int rowBase = (gb % HALF) * 4 + wave;
  int b = rowBase / PP;
  int i = rowBase % PP;
  int Np = meta[b*4+0], Nn = meta[b*4+1];
  int Ncount = isPos ? Np : Nn;
  unsigned short* buf = isPos ? GposF : EnegF;
  char* dst = (char*)buf + ((size_t)b*NTILES + (i>>4))*TILE_BYTES
            + (lane>>3)*1024 + (((i&15) + ((lane>>1)&3)*16) << 4);

  if (i >= Ncount){
    if (i < ((Ncount + 15) & ~15) && !(lane & 1))
      *(uint4*)dst = make_uint4(0u,0u,0u,0u);
    return;
  }
  const int* idx = isPos ? posIdx : negIdx;
  int p = idx[b*PP + i];
  size_t base = ((size_t)b * PP + p) * HH + lane * 4;

  if (isPos){
    float4 g4 = *reinterpret_cast<const float4*>(greek + base);
    float ssg = waveReduceSum(g4.x*g4.x + g4.y*g4.y + g4.z*g4.z + g4.w*g4.w);
    float gs = 1.0f / fmaxf(sqrtf(ssg), 1e-12f);
    float gx = g4.x*gs, gy = g4.y*gs, gz = g4.z*gs, gw = g4.w*gs;
    unsigned u0 = (unsigned)f2bf(gx) | ((unsigned)f2bf(gy) << 16);
    unsigned u1 = (unsigned)f2bf(gz) | ((unsigned)f2bf(gw) << 16);
    unsigned o0 = __shfl_xor(u0, 1), o1 = __shfl_xor(u1, 1);
    if (!(lane & 1)) *(uint4*)dst = make_uint4(u0, u1, o0, o1);
    float4 e4 = *reinterpret_cast<const float4*>(english + base);
    float sse = waveReduceSum(e4.x*e4.x + e4.y*e4.y + e4.z*e4.z + e4.w*e4.w);
    float es = 1.0f / fmaxf(sqrtf(sse), 1e-12f);
    float d = waveReduceSum((gx*e4.x + gy*e4.y + gz*e4.z + gw*e4.w) * es);
    if (lane == 0) diag[b*PP + i] = d;
  } else {
    float4 e4 = *reinterpret_cast<const float4*>(english + base);
    float sse = waveReduceSum(e4.x*e4.x + e4.y*e4.y + e4.z*e4.z + e4.w*e4.w);
    float es = 1.0f / fmaxf(sqrtf(sse), 1e-12f);
    unsigned u0 = (unsigned)f2bf(e4.x*es) | ((unsigned)f2bf(e4.y*es) << 16);
    unsigned u1 = (unsigned)f2bf(e4.z*es) | ((unsigned)f2bf(e4.w*es) << 16);
    unsigned o0 = __shfl_xor(u0, 1), o1 = __shfl_xor(u1, 1);
    if (!(lane & 1)) *(uint4*)dst = make_uint4(u0, u1, o0, o1);
  }
}

// ---------------- K3: MFMA exp-sums, triple-buffered counted-vmcnt pipeline ----------------
// 1-D grid, L = rb*32 + (b*8+chunk) so L%8 == chunk -> all blocks sharing a
// (b,chunk) B-slice land on one XCD (L2-local B re-reads).
// Per tile-phase: waitvm(counted) -> s_barrier -> stage t+2 -> ds_read+MFMA+exp(t).
// Stage AFTER barrier: buffer being overwritten (tile t-1) was consumed by all
// waves before they passed this barrier. vmcnt math: outstanding at wait = {t,t+1}
// (2 loads each, per-wave) -> vmcnt(2) releases exactly tile t; tail uses vmcnt(0).
__global__ void __launch_bounds__(256, 4)
k_loss(const unsigned short* __restrict__ GposF,
       const unsigned short* __restrict__ EnegF,
       const int* __restrict__ meta,
       float* __restrict__ Spart){
  int L = blockIdx.x;
  int rb = L >> 5;
  int pair = L & 31;
  int b = pair >> 3, chunk = pair & 7;
  int Np = meta[b*4+0], Nn = meta[b*4+1], ok = meta[b*4+2];
  int i0 = rb * 64;
  if (!ok || i0 >= Np) return;
  int tid = threadIdx.x, wave = tid >> 6, lane = tid & 63;
  int lo16 = lane & 15, hi4 = lane >> 4;
  int NT = (Nn + 15) >> 4;
  int TPC = (NT + JSPLIT - 1) / JSPLIT;
  int t0 = chunk * TPC, t1 = min(NT, t0 + TPC);

  __shared__ __align__(16) char Bs[3][TILE_BYTES];   // 24 KB triple buffer

  // A fragments (one-time, fully coalesced)
  const char* AF = (const char*)GposF + ((size_t)b*NTILES + (i0 >> 4) + wave) * TILE_BYTES;
  bf16x8 a[8];
  #pragma unroll
  for (int kk = 0; kk < 8; kk++)
    a[kk] = *reinterpret_cast<const bf16x8*>(AF + kk*1024 + (lane << 4));

  const char* EF = (const char*)EnegF + (size_t)b * NTILES * TILE_BYTES;
  float s[4] = {0.f, 0.f, 0.f, 0.f};

  if (t0 < t1){
    // prologue: stage t0 (+ t0+1 if present); waits handled in-loop
    {
      const char* src = EF + (size_t)t0*TILE_BYTES + (wave << 11) + (lane << 4);
      char* dstl = &Bs[0][wave << 11];
      gload_lds16(src, dstl);
      gload_lds16(src + 1024, dstl + 1024);
    }
    if (t0 + 1 < t1){
      const char* src = EF + (size_t)(t0+1)*TILE_BYTES + (wave << 11) + (lane << 4);
      char* dstl = &Bs[1][wave << 11];
      gload_lds16(src, dstl);
      gload_lds16(src + 1024, dstl + 1024);
    }
    int cur = 0;
    for (int t = t0; t < t1; t++){
      if (t + 1 < t1) WAITVM(2);     // drain tile t (and, first iter, A-loads)
      else            WAITVM(0);
      __builtin_amdgcn_s_barrier();
      __builtin_amdgcn_sched_barrier(0);

      if (t + 2 < t1){               // overwrites buffer of tile t-1 (consumed)
        int nb = cur + 2; if (nb >= 3) nb -= 3;
        const char* src = EF + (size_t)(t+2)*TILE_BYTES + (wave << 11) + (lane << 4);
        char* dstl = &Bs[nb][wave << 11];
        gload_lds16(src, dstl);
        gload_lds16(src + 1024, dstl + 1024);
      }

      const char* Bt = &Bs[cur][0];
      f32x4 c = {0.f, 0.f, 0.f, 0.f};
      #pragma unroll
      for (int kk = 0; kk < 8; kk++){
        bf16x8 bv = *reinterpret_cast<const bf16x8*>(Bt + kk*1024 + (lane << 4));
        c = __builtin_amdgcn_mfma_f32_16x16x32_bf16(a[kk], bv, c, 0, 0, 0);
      }
      bool cok = (t*16 + lo16) < Nn;
      #pragma unroll
      for (int r = 0; r < 4; r++)
        s[r] += cok ? __expf(c[r] * INV_T) : 0.0f;

      cur = (cur == 2) ? 0 : cur + 1;
    }
  }

  // reduce across the 16 lanes sharing output rows (D: col=lane&15, row=hi4*4+r)
  #pragma unroll
  for (int off = 1; off < 16; off <<= 1){
    #pragma unroll
    for (int r = 0; r < 4; r++) s[r] += __shfl_xor(s[r], off);
  }
  if (lo16 == 0){
    #pragma unroll
    for (int r = 0; r < 4; r++){
      int i = i0 + wave*16 + hi4*4 + r;
      Spart[(((size_t)b*PP + i) << 3) + chunk] = s[r];
    }
  }
}

// ---------------- K4: fold partials -> per-row loss -> mean ----------------
__global__ void k_final(const float* __restrict__ Spart, const float* __restrict__ diag,
                        const int* __restrict__ meta, float* __restrict__ out){
  __shared__ float lds[16];
  int tid = threadIdx.x;
  int np[BB], okk[BB];
  #pragma unroll
  for (int b = 0; b < BB; b++){ np[b] = meta[b*4+0]; okk[b] = meta[b*4+2]; }
  float tot = 0.0f;
  for (int idx = tid; idx < BB*PP; idx += 1024){
    int b = idx >> 12, i = idx & (PP-1);
    if (!okk[b] || i >= np[b]) continue;
    const float4* p = reinterpret_cast<const float4*>(Spart + ((size_t)idx << 3));
    float4 p0 = p[0], p1 = p[1];
    float S = ((p0.x+p0.y)+(p0.z+p0.w)) + ((p1.x+p1.y)+(p1.z+p1.w));
    float dl = diag[idx] * INV_T;
    tot += logf(S + expf(dl)) - dl;
  }
  #pragma unroll
  for (int off = 32; off; off >>= 1) tot += __shfl_xor(tot, off);
  int wave = tid >> 6;
  if ((tid & 63) == 0) lds[wave] = tot;
  __syncthreads();
  if (tid == 0){
    float total = 0.0f;
    #pragma unroll
    for (int w = 0; w < 16; w++) total += lds[w];
    int count = 0;
    #pragma unroll
    for (int b = 0; b < BB; b++) if (okk[b]) count += np[b];
    out[0] = (count == 0) ? 0.0f : total / (float)count;
  }
}

extern "C" void kernel_launch(void* const* d_in, const int* in_sizes, int n_in,
                              void* d_out, int out_size, void* d_ws, size_t ws_size,
                              hipStream_t stream){
  const float* greek   = (const float*)d_in[0];
  const float* english = (const float*)d_in[1];
  const int*   labels  = (const int*)d_in[2];
  float* out = (float*)d_out;

  char* ws = (char*)d_ws;
  size_t off = 0;
  unsigned short* GposF = (unsigned short*)(ws + off); off += (size_t)BB*NTILES*TILE_BYTES; // 8MB
  unsigned short* EnegF = (unsigned short*)(ws + off); off += (size_t)BB*NTILES*TILE_BYTES; // 8MB
  float* Spart  = (float*)(ws + off); off += (size_t)BB*PP*JSPLIT*sizeof(float);  // 512KB
  float* diag   = (float*)(ws + off); off += (size_t)BB*PP*sizeof(float);
  int*   posIdx = (int*)(ws + off);   off += (size_t)BB*PP*sizeof(int);
  int*   negIdx = (int*)(ws + off);   off += (size_t)BB*PP*sizeof(int);
  int*   meta   = (int*)(ws + off);   off += 64;

  k_compact<<<BB, 256, 0, stream>>>(labels, meta, posIdx, negIdx);
  k_norm<<<2*BB*PP/4, 256, 0, stream>>>(greek, english, meta, posIdx, negIdx,
                                        GposF, EnegF, diag);
  k_loss<<<(PP/64)*32, 256, 0, stream>>>(GposF, EnegF, meta, Spart);
  k_final<<<1, 1024, 0, stream>>>(Spart, diag, meta, out);
}